// Round 2
// baseline (363.496 us; speedup 1.0000x reference)
//
#include <hip/hip_runtime.h>
#include <hip/hip_bf16.h>

// GCN on MI355X — R16: k_agg rebuilt around SCALAR edge metadata.
// Theory: agg was latency-x-MLP bound (~8 gathers in flight/wave -> 63G
// lines/s plateau). New agg: csr_s/csr_w read via s_load (address_space(4),
// wave-uniform segment), gather bases in SGPRs (SALU addr math), 16-deep
// gather batches per wave, dinv factored out so weights stay scalar.
// Per-edge vector-pipe cost: ~3 issues (was ~7); MLP 16 (was 8).
// Pipeline (13 dispatches):
//   k_bhist   - per-block bucket histogram -> cnt_all (no atomics)
//               + merged wprep (W->bf16 Wt) + pool/cnt zeroing
//   k_colscan - one wave per bucket shfl-scan of cnt_all columns
//   k_bscan   - exclusive scan over buckets -> bbase
//   k_bucket  - placement only (lbase = bbase + cnt_all precomputed)
//   k_sort    - per-bucket LDS counting sort -> CSR + rowptr/rowend/dinv
//   k_wfgemm1 - FUSED: wfill blocks (csr_w[e]=dinv[csr_s[e]]) + GEMM-1 blocks
//   k_agg x3  - ONE node per wave; scalar s/w; SADDR ushort gathers.
//   k_gemm x2 - MFMA 16x16x32 bf16, bias+relu+cast fused
//   k_pool    - run-length pre-reduce (RULE from R3/R13: never >~100
//               atomics/address; pre-reduce first)
//   k_final
// All ws-derived loop bounds are clamped (rocprof counter-replay safety).

#define BSHIFT 7
#define BNODES (1 << BSHIFT)
#define EPB    8192
#define MAXDEG 8192
#define MAXBUCKET 32768

typedef __attribute__((ext_vector_type(8))) short bf16x8;
typedef __attribute__((ext_vector_type(4))) float f32x4;

#define KAS __attribute__((address_space(4)))

// CK-style: global pointer -> constant address space (forces s_load path).
template <typename T>
__device__ __forceinline__ const KAS T* kptr(const T* p) {
    return (const KAS T*)(unsigned long long)p;
}

__device__ __forceinline__ void atomAddF(float* p, float v) {
#if defined(__gfx90a__) || defined(__gfx940__) || defined(__gfx941__) || defined(__gfx942__) || defined(__gfx950__)
    unsafeAtomicAdd(p, v);
#else
    atomicAdd(p, v);
#endif
}

__device__ __forceinline__ unsigned short f2bf(float x) {   // RNE fp32->bf16
    unsigned u = __float_as_uint(x);
    u += 0x7FFFu + ((u >> 16) & 1u);
    return (unsigned short)(u >> 16);
}
__device__ __forceinline__ float bf2f(unsigned short b) {
    return __uint_as_float((unsigned)b << 16);
}

// ---------------- histogram + weight prep + pool zeroing ----------------
__global__ __launch_bounds__(256)
void k_bhist(const int* __restrict__ dst, int* __restrict__ cnt_all,
             int nE, int nBuckets, int binBlocks,
             const float* __restrict__ W1, const float* __restrict__ W2,
             const float* __restrict__ W3, unsigned short* __restrict__ Wt,
             float* __restrict__ pool, int poolN) {
    if (blockIdx.x >= binBlocks) {
        int li = blockIdx.x - binBlocks;          // 0..2 wprep, 3 = pool zero
        if (li < 3) {
            const float* W = (li == 0) ? W1 : ((li == 1) ? W2 : W3);
            unsigned short* o = Wt + li * 4096;
            for (int idx = threadIdx.x; idx < 4096; idx += 256) {
                int h = idx >> 6, k = idx & 63;
                o[idx] = f2bf(W[k * 64 + h]);
            }
        } else {
            for (int i = threadIdx.x; i < poolN; i += 256) pool[i] = 0.f;
        }
        return;
    }
    __shared__ int cnt[1024];
    const int t = threadIdx.x;
    const int blk = blockIdx.x * EPB;
    for (int b = t; b < nBuckets; b += 256) cnt[b] = 0;
    __syncthreads();
#pragma unroll 4
    for (int i = 0; i < EPB / 256; i++) {
        int e = blk + i * 256 + t;
        if (e < nE) atomicAdd(&cnt[dst[e] >> BSHIFT], 1);
    }
    __syncthreads();
    for (int b = t; b < nBuckets; b += 256)
        cnt_all[(size_t)blockIdx.x * nBuckets + b] = cnt[b];
}

// ---------------- column scan: one wave per bucket ----------------
__global__ __launch_bounds__(256)
void k_colscan(int* __restrict__ cnt_all, int* __restrict__ bcnt,
               int nBlocks, int nBuckets) {
    const int lane = threadIdx.x & 63;
    const int b = blockIdx.x * 4 + (threadIdx.x >> 6);
    if (b >= nBuckets) return;
    int running = 0;
    for (int c = 0; c < nBlocks; c += 64) {
        int blk = c + lane;
        int v = (blk < nBlocks) ? cnt_all[(size_t)blk * nBuckets + b] : 0;
        int incl = v;
#pragma unroll
        for (int off = 1; off < 64; off <<= 1) {
            int tv = __shfl_up(incl, off);
            if (lane >= off) incl += tv;
        }
        if (blk < nBlocks) cnt_all[(size_t)blk * nBuckets + b] = running + (incl - v);
        running += __shfl(incl, 63);
    }
    if (lane == 0) bcnt[b] = running;
}

// ---------------- bucket scan (nb <= 1024) -> bbase ----------------
__global__ void k_bscan(const int* __restrict__ bcnt, int* __restrict__ bbase,
                        int nb, int nE) {
    __shared__ int s[256];
    const int t = threadIdx.x;
    const int base = t * 4;
    int v0 = (base + 0 < nb) ? bcnt[base + 0] : 0;
    int v1 = (base + 1 < nb) ? bcnt[base + 1] : 0;
    int v2 = (base + 2 < nb) ? bcnt[base + 2] : 0;
    int v3 = (base + 3 < nb) ? bcnt[base + 3] : 0;
    int tsum = v0 + v1 + v2 + v3;
    s[t] = tsum;
    __syncthreads();
    for (int off = 1; off < 256; off <<= 1) {
        int val = 0;
        if (t >= off) val = s[t - off];
        __syncthreads();
        if (t >= off) s[t] += val;
        __syncthreads();
    }
    int excl = s[t] - tsum;
    if (base + 0 < nb) bbase[base + 0] = excl;
    if (base + 1 < nb) bbase[base + 1] = excl + v0;
    if (base + 2 < nb) bbase[base + 2] = excl + v0 + v1;
    if (base + 3 < nb) bbase[base + 3] = excl + v0 + v1 + v2;
    if (t == 0) bbase[nb] = nE;
}

// ---------------- bucket placement ----------------
__global__ __launch_bounds__(256)
void k_bucket(const int* __restrict__ src, const int* __restrict__ dst,
              const int* __restrict__ bbase, const int* __restrict__ cnt_all,
              int* __restrict__ staging, int nE, int nBuckets) {
    __shared__ int cnt[1024];
    __shared__ int lbase[1024];
    const int t = threadIdx.x;
    const int blk = blockIdx.x * EPB;

    for (int b = t; b < nBuckets; b += 256) {
        lbase[b] = bbase[b] + cnt_all[(size_t)blockIdx.x * nBuckets + b];
        cnt[b] = 0;
    }
    __syncthreads();
#pragma unroll 4
    for (int i = 0; i < EPB / 256; i++) {
        int e = blk + i * 256 + t;
        if (e < nE) {
            int s0 = src[e], d0 = dst[e];
            int b = d0 >> BSHIFT;
            int off = atomicAdd(&cnt[b], 1);
            int pos = lbase[b] + off;
            if ((unsigned)pos < (unsigned)nE)
                staging[pos] = (s0 << BSHIFT) | (d0 & (BNODES - 1));
        }
    }
}

// ---------------- per-bucket counting sort -> CSR + rowptr/rowend/dinv ----------
__global__ __launch_bounds__(256)
void k_sort(const int* __restrict__ staging, const int* __restrict__ bbase,
            int* __restrict__ csr_s, int* __restrict__ rowptr,
            int* __restrict__ rowend, float* __restrict__ dinv,
            int n, int nE) {
    __shared__ int c[BNODES];
    __shared__ int sc[BNODES];
    __shared__ int cur[BNODES];
    const int t = threadIdx.x;
    const int b = blockIdx.x;
    const int node0 = b << BSHIFT;

    int seg0 = bbase[b];
    int seg1 = bbase[b + 1];
    seg0 = max(0, min(seg0, nE));
    seg1 = max(seg0, min(seg1, nE));
    seg1 = min(seg1, seg0 + MAXBUCKET);

    if (t < BNODES) c[t] = 0;
    __syncthreads();
    for (int e = seg0 + t; e < seg1; e += 256)
        atomicAdd(&c[staging[e] & (BNODES - 1)], 1);
    __syncthreads();
    if (t < BNODES) sc[t] = c[t];
    __syncthreads();
    for (int off = 1; off < BNODES; off <<= 1) {
        int v = 0;
        if (t >= off && t < BNODES) v = sc[t - off];
        __syncthreads();
        if (t >= off && t < BNODES) sc[t] += v;
        __syncthreads();
    }
    if (t < BNODES) {
        int excl = sc[t] - c[t];
        cur[t] = excl;
        int node = node0 + t;
        if (node < n) {
            rowptr[node] = seg0 + excl;
            rowend[node] = seg0 + excl + c[t];
            dinv[node]   = rsqrtf((float)c[t] + 1.0f);
        }
    }
    __syncthreads();
    for (int e = seg0 + t; e < seg1; e += 256) {
        int p = staging[e];
        int l = p & (BNODES - 1);
        int pos = seg0 + atomicAdd(&cur[l], 1);
        if ((unsigned)pos < (unsigned)nE)
            csr_s[pos] = ((unsigned)p) >> BSHIFT;
    }
}

// ---------------- MFMA GEMM body (shared by k_gemm and k_wfgemm1) -------------
template<bool RELU, typename AT>
__device__ __forceinline__
void gemm_body(int bid, const AT* __restrict__ in,
               const unsigned short* __restrict__ Wt,
               const float* __restrict__ bias,
               unsigned short* __restrict__ out, int n) {
    const int lane = threadIdx.x & 63;
    const int wid  = threadIdx.x >> 6;
    const int col  = lane & 15;
    const int quad = lane >> 4;
    const int node0w = bid * 64 + wid * 16;
    const int nodeA  = node0w + col;
    const bool validA = nodeA < n;

    f32x4 zero4 = {0.f, 0.f, 0.f, 0.f};
    f32x4 acc0 = zero4, acc1 = zero4, acc2 = zero4, acc3 = zero4;

#pragma unroll
    for (int ks = 0; ks < 64; ks += 32) {
        const int kb = ks + quad * 8;
        float a[8];
        if constexpr (sizeof(AT) == 4) {
            float4 a0 = make_float4(0.f, 0.f, 0.f, 0.f);
            float4 a1 = make_float4(0.f, 0.f, 0.f, 0.f);
            if (validA) {
                a0 = *(const float4*)((const float*)in + (size_t)nodeA * 64 + kb);
                a1 = *(const float4*)((const float*)in + (size_t)nodeA * 64 + kb + 4);
            }
            a[0] = a0.x; a[1] = a0.y; a[2] = a0.z; a[3] = a0.w;
            a[4] = a1.x; a[5] = a1.y; a[6] = a1.z; a[7] = a1.w;
        } else {
            ushort4 h0 = make_ushort4(0, 0, 0, 0), h1 = make_ushort4(0, 0, 0, 0);
            if (validA) {
                h0 = *(const ushort4*)((const unsigned short*)in + (size_t)nodeA * 64 + kb);
                h1 = *(const ushort4*)((const unsigned short*)in + (size_t)nodeA * 64 + kb + 4);
            }
            a[0] = bf2f(h0.x); a[1] = bf2f(h0.y); a[2] = bf2f(h0.z); a[3] = bf2f(h0.w);
            a[4] = bf2f(h1.x); a[5] = bf2f(h1.y); a[6] = bf2f(h1.z); a[7] = bf2f(h1.w);
        }
        if (RELU) {
#pragma unroll
            for (int i = 0; i < 8; i++) a[i] = fmaxf(a[i] + bias[kb + i], 0.f);
        }
        bf16x8 af;
#pragma unroll
        for (int i = 0; i < 8; i++) af[i] = (short)f2bf(a[i]);

        const bf16x8 b0f = *(const bf16x8*)(Wt + ((0 * 16 + col) * 64 + kb));
        const bf16x8 b1f = *(const bf16x8*)(Wt + ((1 * 16 + col) * 64 + kb));
        const bf16x8 b2f = *(const bf16x8*)(Wt + ((2 * 16 + col) * 64 + kb));
        const bf16x8 b3f = *(const bf16x8*)(Wt + ((3 * 16 + col) * 64 + kb));
        acc0 = __builtin_amdgcn_mfma_f32_16x16x32_bf16(af, b0f, acc0, 0, 0, 0);
        acc1 = __builtin_amdgcn_mfma_f32_16x16x32_bf16(af, b1f, acc1, 0, 0, 0);
        acc2 = __builtin_amdgcn_mfma_f32_16x16x32_bf16(af, b2f, acc2, 0, 0, 0);
        acc3 = __builtin_amdgcn_mfma_f32_16x16x32_bf16(af, b3f, acc3, 0, 0, 0);
    }

#pragma unroll
    for (int r = 0; r < 4; r++) {
        int nn = node0w + quad * 4 + r;
        if (nn < n) {
            size_t base = (size_t)nn * 64 + col;
            out[base +  0] = f2bf(acc0[r]);
            out[base + 16] = f2bf(acc1[r]);
            out[base + 32] = f2bf(acc2[r]);
            out[base + 48] = f2bf(acc3[r]);
        }
    }
}

template<bool RELU, typename AT>
__global__ __launch_bounds__(256)
void k_gemm(const AT* __restrict__ in, const unsigned short* __restrict__ Wt,
            const float* __restrict__ bias, unsigned short* __restrict__ out, int n) {
    gemm_body<RELU, AT>(blockIdx.x, in, Wt, bias, out, n);
}

// ---------------- FUSED: wfill blocks + layer-1 GEMM blocks -------------------
__global__ __launch_bounds__(256)
void k_wfgemm1(const int* __restrict__ csr_s, const float* __restrict__ dinv,
               float* __restrict__ csr_w, int nE, int n, int wfB,
               const float* __restrict__ x, const unsigned short* __restrict__ Wt,
               unsigned short* __restrict__ hW) {
    if (blockIdx.x < wfB) {
        int e = blockIdx.x * 256 + threadIdx.x;
        if (e < nE) {
            int s = csr_s[e];
            s = max(0, min(s, n - 1));
            csr_w[e] = dinv[s];
        }
        return;
    }
    gemm_body<false, float>(blockIdx.x - wfB, x, Wt, nullptr, hW, n);
}

// ---------------- aggregation: ONE node per wave, scalar edge metadata --------
// R16: row segment is wave-uniform -> csr_s/csr_w via s_load (AS4), gather
// base in SGPR (SALU addr), 16 gathers in flight per batch. dinv factored
// out of the weighted sum so w stays a pure scalar (v_fmac acc, s_w, v_h).
// Tail lanes gather row 0 (L1-resident) with w=0 -> no extra L2 traffic.
template<int LAYER>
__global__ __launch_bounds__(256)
void k_agg(const unsigned short* __restrict__ hW, const int* __restrict__ rowptr,
           const int* __restrict__ rowend, const int* __restrict__ csr_s,
           const float* __restrict__ csr_w, const float* __restrict__ dinv,
           unsigned short* __restrict__ aggb, int n, int nE) {
    const int lane = threadIdx.x & 63;
    const int wid  = threadIdx.x >> 6;
    const int node = blockIdx.x * 4 + wid;
    if (node >= n) return;

    int rowA = __builtin_amdgcn_readfirstlane(rowptr[node]);
    int endA = __builtin_amdgcn_readfirstlane(rowend[node]);
    rowA = max(0, min(rowA, nE)); endA = max(rowA, min(endA, nE));
    endA = min(endA, rowA + MAXDEG);
    const float diA = __uint_as_float(
        __builtin_amdgcn_readfirstlane(__float_as_uint(dinv[node])));

    // self term: result = diA * (sum_e w_e*h_e + diA*h_self)
    float acc0 = diA * bf2f(hW[(size_t)node * 64 + lane]);
    float acc1 = 0.f, acc2 = 0.f, acc3 = 0.f;
    const int nm1 = n - 1;

    for (int b = rowA; b < endA; b += 16) {
        const KAS int*   sp = kptr(csr_s + b);
        const KAS float* wp = kptr(csr_w + b);
        const int rem = endA - b;            // scalar

        int   sidx[16];
        float w[16];
#pragma unroll
        for (int j = 0; j < 16; j++) {
            int s = sp[j];                   // s_load (merged dwordx16)
            s = max(0, min(s, nm1));
            sidx[j] = (j < rem) ? s : 0;     // tail -> row 0 (L1-hot)
            w[j]    = (j < rem) ? wp[j] : 0.f;
        }
        float h[16];
#pragma unroll
        for (int j = 0; j < 16; j++)         // 16 SADDR gathers in flight
            h[j] = bf2f(hW[(size_t)sidx[j] * 64 + lane]);
#pragma unroll
        for (int j = 0; j < 16; j += 4) {
            acc0 += w[j]     * h[j];
            acc1 += w[j + 1] * h[j + 1];
            acc2 += w[j + 2] * h[j + 2];
            acc3 += w[j + 3] * h[j + 3];
        }
    }
    float r = diA * ((acc0 + acc1) + (acc2 + acc3));
    aggb[(size_t)node * 64 + lane] = f2bf(r);
}

// ---------------- pooling (run-length pre-reduce; few atomics) ----------------
__global__ void k_pool(const unsigned short* __restrict__ aggb,
                       const int* __restrict__ batch,
                       float* __restrict__ pool, float* __restrict__ cnt, int n) {
    const int lane = threadIdx.x;       // 64 threads
    const int base = blockIdx.x * 64;
    int g_cur = -1, run = 0;
    float acc = 0.f;
    for (int j = 0; j < 64; j++) {
        int node = base + j;
        if (node >= n) break;
        int g = batch[node];
        if (g != g_cur) {
            if (g_cur >= 0) {
                atomAddF(&pool[g_cur * 64 + lane], acc);
                if (lane == 0) atomAddF(&cnt[g_cur], (float)run);
            }
            g_cur = g; acc = 0.f; run = 0;
        }
        acc += bf2f(aggb[(size_t)node * 64 + lane]);
        run++;
    }
    if (g_cur >= 0) {
        atomAddF(&pool[g_cur * 64 + lane], acc);
        if (lane == 0) atomAddF(&cnt[g_cur], (float)run);
    }
}

// ---------------- classifier ----------------
__global__ void k_final(const float* __restrict__ pool, const float* __restrict__ cnt,
                        const float* __restrict__ b3, const float* __restrict__ Wl,
                        const float* __restrict__ bl, float* __restrict__ out) {
    __shared__ float s[64];
    const int g = blockIdx.x, t = threadIdx.x;
    float c = fmaxf(cnt[g], 1.0f);
    s[t] = pool[g * 64 + t] / c + b3[t];
    __syncthreads();
    if (t < 10) {
        float acc = bl[t];
#pragma unroll
        for (int k = 0; k < 64; k++) acc += s[k] * Wl[k * 10 + t];
        out[g * 10 + t] = acc;
    }
}

extern "C" void kernel_launch(void* const* d_in, const int* in_sizes, int n_in,
                              void* d_out, int out_size, void* d_ws, size_t ws_size,
                              hipStream_t stream) {
    const float* x   = (const float*)d_in[0];
    const int*   ei  = (const int*)d_in[1];
    const int*   bat = (const int*)d_in[2];
    const float* W1  = (const float*)d_in[3];
    const float* b1  = (const float*)d_in[4];
    const float* W2  = (const float*)d_in[5];
    const float* b2  = (const float*)d_in[6];
    const float* W3  = (const float*)d_in[7];
    const float* b3  = (const float*)d_in[8];
    const float* Wl  = (const float*)d_in[9];
    const float* bl  = (const float*)d_in[10];
    float* out = (float*)d_out;

    const int N_ = in_sizes[0] / 64;
    const int E_ = in_sizes[1] / 2;
    const int G_ = out_size / 10;
    const int NB_ = (N_ + BNODES - 1) >> BSHIFT;
    const int bin_blocks = (E_ + EPB - 1) / EPB;

    // workspace layout
    char* p = (char*)d_ws;
    int*   staging = (int*)p;   p += (size_t)E_ * 4;
    int*   csr_s  = (int*)p;    p += (size_t)E_ * 4;
    float* csr_w  = (float*)p;  p += (size_t)E_ * 4;
    unsigned short* aggb = (unsigned short*)p; p += (size_t)N_ * 64 * 2;
    unsigned short* hW   = (unsigned short*)p; p += (size_t)N_ * 64 * 2;
    float* dinv   = (float*)p;  p += (size_t)N_ * 4;
    int*   rowptr = (int*)p;    p += (size_t)N_ * 4;
    int*   rowend = (int*)p;    p += (size_t)N_ * 4;
    float* pool   = (float*)p;  p += (size_t)G_ * 64 * 4;
    float* cnt    = (float*)p;  p += (size_t)G_ * 4;
    unsigned short* Wt = (unsigned short*)p; p += 3 * 4096 * 2;
    int*   bcnt   = (int*)p;    p += (size_t)(NB_ + 1) * 4;
    int*   bbase  = (int*)p;    p += (size_t)(NB_ + 1) * 4;
    int*   cnt_all = (int*)p;   p += (size_t)bin_blocks * NB_ * 4;

    const int* srcp = ei;
    const int* dstp = ei + E_;

    // pool + cnt zeroed by k_bhist's extra block (they are contiguous)
    k_bhist<<<bin_blocks + 4, 256, 0, stream>>>(dstp, cnt_all, E_, NB_,
                                                bin_blocks, W1, W2, W3, Wt,
                                                pool, G_ * 64 + G_);
    k_colscan<<<(NB_ + 3) / 4, 256, 0, stream>>>(cnt_all, bcnt, bin_blocks, NB_);
    k_bscan<<<1, 256, 0, stream>>>(bcnt, bbase, NB_, E_);
    k_bucket<<<bin_blocks, 256, 0, stream>>>(srcp, dstp, bbase, cnt_all,
                                             staging, E_, NB_);
    k_sort<<<NB_, 256, 0, stream>>>(staging, bbase, csr_s, rowptr, rowend,
                                    dinv, N_, E_);

    const int gemm_blocks = (N_ + 63) / 64;
    const int agg_blocks  = (N_ + 3) / 4;
    const int wf_blocks   = (E_ + 255) / 256;

    // Fused wfill + Layer-1 GEMM
    k_wfgemm1<<<wf_blocks + gemm_blocks, 256, 0, stream>>>(
        csr_s, dinv, csr_w, E_, N_, wf_blocks, x, Wt, hW);
    k_agg<1><<<agg_blocks, 256, 0, stream>>>(hW, rowptr, rowend, csr_s, csr_w,
                                             dinv, aggb, N_, E_);
    // Layer 2
    k_gemm<true, unsigned short><<<gemm_blocks, 256, 0, stream>>>(aggb, Wt + 4096,
                                                                  b1, hW, N_);
    k_agg<2><<<agg_blocks, 256, 0, stream>>>(hW, rowptr, rowend, csr_s, csr_w,
                                             dinv, aggb, N_, E_);
    // Layer 3
    k_gemm<true, unsigned short><<<gemm_blocks, 256, 0, stream>>>(aggb, Wt + 8192,
                                                                  b2, hW, N_);
    k_agg<3><<<agg_blocks, 256, 0, stream>>>(hW, rowptr, rowend, csr_s, csr_w,
                                             dinv, aggb, N_, E_);

    // Pool (b3 folded into final) + classifier
    k_pool<<<(N_ + 63) / 64, 64, 0, stream>>>(aggb, bat, pool, cnt, N_);
    k_final<<<G_, 64, 0, stream>>>(pool, cnt, b3, Wl, bl, out);
}

// Round 3
// 349.421 us; speedup vs baseline: 1.0403x; 1.0403x over previous
//
#include <hip/hip_runtime.h>
#include <hip/hip_bf16.h>

// GCN on MI355X — R17: k_agg packed gathers — 8 rows per global_load_dwordx4.
// Evidence: R14/R15/R16 all plateau at ~29-30 G gather-INSTRUCTIONS/s
// regardless of VALU load (50%->21%), MLP depth (8->16), or scalar/vector
// metadata. All prior variants used 1 instr : 2 lines (128B row / wave).
// This round changes the ratio to 1 instr : 16 lines (8 rows/instr):
//   lane l -> row-group g=l>>3 (edge slot), dim-slot d=l&7 (16B of the row).
//   csr_s/csr_w vector-loaded per lane at [b+g] (sequential, cached) so each
//   lane holds its group's w in a VGPR natively. 3x shfl_xor fold per NODE.
// If transaction-bound: agg ~51 -> ~20-25us. If line-bound: ~43us (proves
// line model -> fp8 rows next).
// Pipeline (13 dispatches):
//   k_bhist, k_colscan, k_bscan, k_bucket, k_sort  - CSR build
//   k_wfgemm1 - FUSED wfill + GEMM-1;  k_agg x3;  k_gemm x2
//   k_pool    - run-length pre-reduce;  k_final
// All ws-derived loop bounds are clamped (rocprof counter-replay safety).

#define BSHIFT 7
#define BNODES (1 << BSHIFT)
#define EPB    8192
#define MAXDEG 8192
#define MAXBUCKET 32768

typedef __attribute__((ext_vector_type(8))) short bf16x8;
typedef __attribute__((ext_vector_type(4))) float f32x4;
typedef __attribute__((ext_vector_type(8))) unsigned short u16x8;

__device__ __forceinline__ void atomAddF(float* p, float v) {
#if defined(__gfx90a__) || defined(__gfx940__) || defined(__gfx941__) || defined(__gfx942__) || defined(__gfx950__)
    unsafeAtomicAdd(p, v);
#else
    atomicAdd(p, v);
#endif
}

__device__ __forceinline__ unsigned short f2bf(float x) {   // RNE fp32->bf16
    unsigned u = __float_as_uint(x);
    u += 0x7FFFu + ((u >> 16) & 1u);
    return (unsigned short)(u >> 16);
}
__device__ __forceinline__ float bf2f(unsigned short b) {
    return __uint_as_float((unsigned)b << 16);
}

// ---------------- histogram + weight prep + pool zeroing ----------------
__global__ __launch_bounds__(256)
void k_bhist(const int* __restrict__ dst, int* __restrict__ cnt_all,
             int nE, int nBuckets, int binBlocks,
             const float* __restrict__ W1, const float* __restrict__ W2,
             const float* __restrict__ W3, unsigned short* __restrict__ Wt,
             float* __restrict__ pool, int poolN) {
    if (blockIdx.x >= binBlocks) {
        int li = blockIdx.x - binBlocks;          // 0..2 wprep, 3 = pool zero
        if (li < 3) {
            const float* W = (li == 0) ? W1 : ((li == 1) ? W2 : W3);
            unsigned short* o = Wt + li * 4096;
            for (int idx = threadIdx.x; idx < 4096; idx += 256) {
                int h = idx >> 6, k = idx & 63;
                o[idx] = f2bf(W[k * 64 + h]);
            }
        } else {
            for (int i = threadIdx.x; i < poolN; i += 256) pool[i] = 0.f;
        }
        return;
    }
    __shared__ int cnt[1024];
    const int t = threadIdx.x;
    const int blk = blockIdx.x * EPB;
    for (int b = t; b < nBuckets; b += 256) cnt[b] = 0;
    __syncthreads();
#pragma unroll 4
    for (int i = 0; i < EPB / 256; i++) {
        int e = blk + i * 256 + t;
        if (e < nE) atomicAdd(&cnt[dst[e] >> BSHIFT], 1);
    }
    __syncthreads();
    for (int b = t; b < nBuckets; b += 256)
        cnt_all[(size_t)blockIdx.x * nBuckets + b] = cnt[b];
}

// ---------------- column scan: one wave per bucket ----------------
__global__ __launch_bounds__(256)
void k_colscan(int* __restrict__ cnt_all, int* __restrict__ bcnt,
               int nBlocks, int nBuckets) {
    const int lane = threadIdx.x & 63;
    const int b = blockIdx.x * 4 + (threadIdx.x >> 6);
    if (b >= nBuckets) return;
    int running = 0;
    for (int c = 0; c < nBlocks; c += 64) {
        int blk = c + lane;
        int v = (blk < nBlocks) ? cnt_all[(size_t)blk * nBuckets + b] : 0;
        int incl = v;
#pragma unroll
        for (int off = 1; off < 64; off <<= 1) {
            int tv = __shfl_up(incl, off);
            if (lane >= off) incl += tv;
        }
        if (blk < nBlocks) cnt_all[(size_t)blk * nBuckets + b] = running + (incl - v);
        running += __shfl(incl, 63);
    }
    if (lane == 0) bcnt[b] = running;
}

// ---------------- bucket scan (nb <= 1024) -> bbase ----------------
__global__ void k_bscan(const int* __restrict__ bcnt, int* __restrict__ bbase,
                        int nb, int nE) {
    __shared__ int s[256];
    const int t = threadIdx.x;
    const int base = t * 4;
    int v0 = (base + 0 < nb) ? bcnt[base + 0] : 0;
    int v1 = (base + 1 < nb) ? bcnt[base + 1] : 0;
    int v2 = (base + 2 < nb) ? bcnt[base + 2] : 0;
    int v3 = (base + 3 < nb) ? bcnt[base + 3] : 0;
    int tsum = v0 + v1 + v2 + v3;
    s[t] = tsum;
    __syncthreads();
    for (int off = 1; off < 256; off <<= 1) {
        int val = 0;
        if (t >= off) val = s[t - off];
        __syncthreads();
        if (t >= off) s[t] += val;
        __syncthreads();
    }
    int excl = s[t] - tsum;
    if (base + 0 < nb) bbase[base + 0] = excl;
    if (base + 1 < nb) bbase[base + 1] = excl + v0;
    if (base + 2 < nb) bbase[base + 2] = excl + v0 + v1;
    if (base + 3 < nb) bbase[base + 3] = excl + v0 + v1 + v2;
    if (t == 0) bbase[nb] = nE;
}

// ---------------- bucket placement ----------------
__global__ __launch_bounds__(256)
void k_bucket(const int* __restrict__ src, const int* __restrict__ dst,
              const int* __restrict__ bbase, const int* __restrict__ cnt_all,
              int* __restrict__ staging, int nE, int nBuckets) {
    __shared__ int cnt[1024];
    __shared__ int lbase[1024];
    const int t = threadIdx.x;
    const int blk = blockIdx.x * EPB;

    for (int b = t; b < nBuckets; b += 256) {
        lbase[b] = bbase[b] + cnt_all[(size_t)blockIdx.x * nBuckets + b];
        cnt[b] = 0;
    }
    __syncthreads();
#pragma unroll 4
    for (int i = 0; i < EPB / 256; i++) {
        int e = blk + i * 256 + t;
        if (e < nE) {
            int s0 = src[e], d0 = dst[e];
            int b = d0 >> BSHIFT;
            int off = atomicAdd(&cnt[b], 1);
            int pos = lbase[b] + off;
            if ((unsigned)pos < (unsigned)nE)
                staging[pos] = (s0 << BSHIFT) | (d0 & (BNODES - 1));
        }
    }
}

// ---------------- per-bucket counting sort -> CSR + rowptr/rowend/dinv ----------
__global__ __launch_bounds__(256)
void k_sort(const int* __restrict__ staging, const int* __restrict__ bbase,
            int* __restrict__ csr_s, int* __restrict__ rowptr,
            int* __restrict__ rowend, float* __restrict__ dinv,
            int n, int nE) {
    __shared__ int c[BNODES];
    __shared__ int sc[BNODES];
    __shared__ int cur[BNODES];
    const int t = threadIdx.x;
    const int b = blockIdx.x;
    const int node0 = b << BSHIFT;

    int seg0 = bbase[b];
    int seg1 = bbase[b + 1];
    seg0 = max(0, min(seg0, nE));
    seg1 = max(seg0, min(seg1, nE));
    seg1 = min(seg1, seg0 + MAXBUCKET);

    if (t < BNODES) c[t] = 0;
    __syncthreads();
    for (int e = seg0 + t; e < seg1; e += 256)
        atomicAdd(&c[staging[e] & (BNODES - 1)], 1);
    __syncthreads();
    if (t < BNODES) sc[t] = c[t];
    __syncthreads();
    for (int off = 1; off < BNODES; off <<= 1) {
        int v = 0;
        if (t >= off && t < BNODES) v = sc[t - off];
        __syncthreads();
        if (t >= off && t < BNODES) sc[t] += v;
        __syncthreads();
    }
    if (t < BNODES) {
        int excl = sc[t] - c[t];
        cur[t] = excl;
        int node = node0 + t;
        if (node < n) {
            rowptr[node] = seg0 + excl;
            rowend[node] = seg0 + excl + c[t];
            dinv[node]   = rsqrtf((float)c[t] + 1.0f);
        }
    }
    __syncthreads();
    for (int e = seg0 + t; e < seg1; e += 256) {
        int p = staging[e];
        int l = p & (BNODES - 1);
        int pos = seg0 + atomicAdd(&cur[l], 1);
        if ((unsigned)pos < (unsigned)nE)
            csr_s[pos] = ((unsigned)p) >> BSHIFT;
    }
}

// ---------------- MFMA GEMM body (shared by k_gemm and k_wfgemm1) -------------
template<bool RELU, typename AT>
__device__ __forceinline__
void gemm_body(int bid, const AT* __restrict__ in,
               const unsigned short* __restrict__ Wt,
               const float* __restrict__ bias,
               unsigned short* __restrict__ out, int n) {
    const int lane = threadIdx.x & 63;
    const int wid  = threadIdx.x >> 6;
    const int col  = lane & 15;
    const int quad = lane >> 4;
    const int node0w = bid * 64 + wid * 16;
    const int nodeA  = node0w + col;
    const bool validA = nodeA < n;

    f32x4 zero4 = {0.f, 0.f, 0.f, 0.f};
    f32x4 acc0 = zero4, acc1 = zero4, acc2 = zero4, acc3 = zero4;

#pragma unroll
    for (int ks = 0; ks < 64; ks += 32) {
        const int kb = ks + quad * 8;
        float a[8];
        if constexpr (sizeof(AT) == 4) {
            float4 a0 = make_float4(0.f, 0.f, 0.f, 0.f);
            float4 a1 = make_float4(0.f, 0.f, 0.f, 0.f);
            if (validA) {
                a0 = *(const float4*)((const float*)in + (size_t)nodeA * 64 + kb);
                a1 = *(const float4*)((const float*)in + (size_t)nodeA * 64 + kb + 4);
            }
            a[0] = a0.x; a[1] = a0.y; a[2] = a0.z; a[3] = a0.w;
            a[4] = a1.x; a[5] = a1.y; a[6] = a1.z; a[7] = a1.w;
        } else {
            ushort4 h0 = make_ushort4(0, 0, 0, 0), h1 = make_ushort4(0, 0, 0, 0);
            if (validA) {
                h0 = *(const ushort4*)((const unsigned short*)in + (size_t)nodeA * 64 + kb);
                h1 = *(const ushort4*)((const unsigned short*)in + (size_t)nodeA * 64 + kb + 4);
            }
            a[0] = bf2f(h0.x); a[1] = bf2f(h0.y); a[2] = bf2f(h0.z); a[3] = bf2f(h0.w);
            a[4] = bf2f(h1.x); a[5] = bf2f(h1.y); a[6] = bf2f(h1.z); a[7] = bf2f(h1.w);
        }
        if (RELU) {
#pragma unroll
            for (int i = 0; i < 8; i++) a[i] = fmaxf(a[i] + bias[kb + i], 0.f);
        }
        bf16x8 af;
#pragma unroll
        for (int i = 0; i < 8; i++) af[i] = (short)f2bf(a[i]);

        const bf16x8 b0f = *(const bf16x8*)(Wt + ((0 * 16 + col) * 64 + kb));
        const bf16x8 b1f = *(const bf16x8*)(Wt + ((1 * 16 + col) * 64 + kb));
        const bf16x8 b2f = *(const bf16x8*)(Wt + ((2 * 16 + col) * 64 + kb));
        const bf16x8 b3f = *(const bf16x8*)(Wt + ((3 * 16 + col) * 64 + kb));
        acc0 = __builtin_amdgcn_mfma_f32_16x16x32_bf16(af, b0f, acc0, 0, 0, 0);
        acc1 = __builtin_amdgcn_mfma_f32_16x16x32_bf16(af, b1f, acc1, 0, 0, 0);
        acc2 = __builtin_amdgcn_mfma_f32_16x16x32_bf16(af, b2f, acc2, 0, 0, 0);
        acc3 = __builtin_amdgcn_mfma_f32_16x16x32_bf16(af, b3f, acc3, 0, 0, 0);
    }

#pragma unroll
    for (int r = 0; r < 4; r++) {
        int nn = node0w + quad * 4 + r;
        if (nn < n) {
            size_t base = (size_t)nn * 64 + col;
            out[base +  0] = f2bf(acc0[r]);
            out[base + 16] = f2bf(acc1[r]);
            out[base + 32] = f2bf(acc2[r]);
            out[base + 48] = f2bf(acc3[r]);
        }
    }
}

template<bool RELU, typename AT>
__global__ __launch_bounds__(256)
void k_gemm(const AT* __restrict__ in, const unsigned short* __restrict__ Wt,
            const float* __restrict__ bias, unsigned short* __restrict__ out, int n) {
    gemm_body<RELU, AT>(blockIdx.x, in, Wt, bias, out, n);
}

// ---------------- FUSED: wfill blocks + layer-1 GEMM blocks -------------------
__global__ __launch_bounds__(256)
void k_wfgemm1(const int* __restrict__ csr_s, const float* __restrict__ dinv,
               float* __restrict__ csr_w, int nE, int n, int wfB,
               const float* __restrict__ x, const unsigned short* __restrict__ Wt,
               unsigned short* __restrict__ hW) {
    if (blockIdx.x < wfB) {
        int e = blockIdx.x * 256 + threadIdx.x;
        if (e < nE) {
            int s = csr_s[e];
            s = max(0, min(s, n - 1));
            csr_w[e] = dinv[s];
        }
        return;
    }
    gemm_body<false, float>(blockIdx.x - wfB, x, Wt, nullptr, hW, n);
}

// ---------------- aggregation: packed gathers, 8 rows / instruction ----------
// Lane l: edge-slot g=l>>3, dim-slot d=l&7 (dims [d*8, d*8+8) = 16B of row).
// One global_load_dwordx4 per 8 edges (64 lanes x 16B = 8 full bf16 rows).
// csr_s/csr_w loaded per-lane at [b+g]: each lane natively holds its slot's
// w — zero broadcasts in the edge loop. Per-node epilogue: 3x shfl_xor fold
// over slots, g==0 octet adds self term and stores the 128B row.
template<int LAYER>
__global__ __launch_bounds__(256)
void k_agg(const unsigned short* __restrict__ hW, const int* __restrict__ rowptr,
           const int* __restrict__ rowend, const int* __restrict__ csr_s,
           const float* __restrict__ csr_w, const float* __restrict__ dinv,
           unsigned short* __restrict__ aggb, int n, int nE) {
    const int lane  = threadIdx.x & 63;
    const int wid   = threadIdx.x >> 6;
    const int node  = blockIdx.x * 4 + wid;
    if (node >= n) return;
    const int g     = lane >> 3;        // edge slot 0..7
    const int dslot = lane & 7;         // dim slot 0..7

    int rowA = rowptr[node], endA = rowend[node];
    rowA = max(0, min(rowA, nE)); endA = max(rowA, min(endA, nE));
    endA = min(endA, rowA + MAXDEG);
    const float diA = dinv[node];
    const int nm1 = n - 1;

    float acc[8];
#pragma unroll
    for (int i = 0; i < 8; i++) acc[i] = 0.f;

    for (int b = rowA; b < endA; b += 16) {
        const int e0 = b + g;
        const int e1 = b + 8 + g;
        int   s0 = 0, s1 = 0;
        float w0 = 0.f, w1 = 0.f;
        if (e0 < endA) { s0 = csr_s[e0]; w0 = csr_w[e0]; }
        if (e1 < endA) { s1 = csr_s[e1]; w1 = csr_w[e1]; }
        s0 = max(0, min(s0, nm1));
        s1 = max(0, min(s1, nm1));
        const u16x8 h0 = *(const u16x8*)(hW + (size_t)s0 * 64 + dslot * 8);
        const u16x8 h1 = *(const u16x8*)(hW + (size_t)s1 * 64 + dslot * 8);
#pragma unroll
        for (int i = 0; i < 8; i++) {
            acc[i] += w0 * bf2f(h0[i]);
            acc[i] += w1 * bf2f(h1[i]);
        }
    }

    // fold the 8 edge slots (lanes stride-8 apart hold the same dims)
#pragma unroll
    for (int off = 8; off < 64; off <<= 1) {
#pragma unroll
        for (int i = 0; i < 8; i++) acc[i] += __shfl_xor(acc[i], off);
    }

    if (g == 0) {
        const u16x8 hs = *(const u16x8*)(hW + (size_t)node * 64 + dslot * 8);
        u16x8 r;
#pragma unroll
        for (int i = 0; i < 8; i++)
            r[i] = f2bf(diA * (acc[i] + diA * bf2f(hs[i])));
        *(u16x8*)(aggb + (size_t)node * 64 + dslot * 8) = r;
    }
}

// ---------------- pooling (run-length pre-reduce; few atomics) ----------------
__global__ void k_pool(const unsigned short* __restrict__ aggb,
                       const int* __restrict__ batch,
                       float* __restrict__ pool, float* __restrict__ cnt, int n) {
    const int lane = threadIdx.x;       // 64 threads
    const int base = blockIdx.x * 64;
    int g_cur = -1, run = 0;
    float acc = 0.f;
    for (int j = 0; j < 64; j++) {
        int node = base + j;
        if (node >= n) break;
        int g = batch[node];
        if (g != g_cur) {
            if (g_cur >= 0) {
                atomAddF(&pool[g_cur * 64 + lane], acc);
                if (lane == 0) atomAddF(&cnt[g_cur], (float)run);
            }
            g_cur = g; acc = 0.f; run = 0;
        }
        acc += bf2f(aggb[(size_t)node * 64 + lane]);
        run++;
    }
    if (g_cur >= 0) {
        atomAddF(&pool[g_cur * 64 + lane], acc);
        if (lane == 0) atomAddF(&cnt[g_cur], (float)run);
    }
}

// ---------------- classifier ----------------
__global__ void k_final(const float* __restrict__ pool, const float* __restrict__ cnt,
                        const float* __restrict__ b3, const float* __restrict__ Wl,
                        const float* __restrict__ bl, float* __restrict__ out) {
    __shared__ float s[64];
    const int g = blockIdx.x, t = threadIdx.x;
    float c = fmaxf(cnt[g], 1.0f);
    s[t] = pool[g * 64 + t] / c + b3[t];
    __syncthreads();
    if (t < 10) {
        float acc = bl[t];
#pragma unroll
        for (int k = 0; k < 64; k++) acc += s[k] * Wl[k * 10 + t];
        out[g * 10 + t] = acc;
    }
}

extern "C" void kernel_launch(void* const* d_in, const int* in_sizes, int n_in,
                              void* d_out, int out_size, void* d_ws, size_t ws_size,
                              hipStream_t stream) {
    const float* x   = (const float*)d_in[0];
    const int*   ei  = (const int*)d_in[1];
    const int*   bat = (const int*)d_in[2];
    const float* W1  = (const float*)d_in[3];
    const float* b1  = (const float*)d_in[4];
    const float* W2  = (const float*)d_in[5];
    const float* b2  = (const float*)d_in[6];
    const float* W3  = (const float*)d_in[7];
    const float* b3  = (const float*)d_in[8];
    const float* Wl  = (const float*)d_in[9];
    const float* bl  = (const float*)d_in[10];
    float* out = (float*)d_out;

    const int N_ = in_sizes[0] / 64;
    const int E_ = in_sizes[1] / 2;
    const int G_ = out_size / 10;
    const int NB_ = (N_ + BNODES - 1) >> BSHIFT;
    const int bin_blocks = (E_ + EPB - 1) / EPB;

    // workspace layout
    char* p = (char*)d_ws;
    int*   staging = (int*)p;   p += (size_t)E_ * 4;
    int*   csr_s  = (int*)p;    p += (size_t)E_ * 4;
    float* csr_w  = (float*)p;  p += (size_t)E_ * 4;
    unsigned short* aggb = (unsigned short*)p; p += (size_t)N_ * 64 * 2;
    unsigned short* hW   = (unsigned short*)p; p += (size_t)N_ * 64 * 2;
    float* dinv   = (float*)p;  p += (size_t)N_ * 4;
    int*   rowptr = (int*)p;    p += (size_t)N_ * 4;
    int*   rowend = (int*)p;    p += (size_t)N_ * 4;
    float* pool   = (float*)p;  p += (size_t)G_ * 64 * 4;
    float* cnt    = (float*)p;  p += (size_t)G_ * 4;
    unsigned short* Wt = (unsigned short*)p; p += 3 * 4096 * 2;
    int*   bcnt   = (int*)p;    p += (size_t)(NB_ + 1) * 4;
    int*   bbase  = (int*)p;    p += (size_t)(NB_ + 1) * 4;
    int*   cnt_all = (int*)p;   p += (size_t)bin_blocks * NB_ * 4;

    const int* srcp = ei;
    const int* dstp = ei + E_;

    // pool + cnt zeroed by k_bhist's extra block (they are contiguous)
    k_bhist<<<bin_blocks + 4, 256, 0, stream>>>(dstp, cnt_all, E_, NB_,
                                                bin_blocks, W1, W2, W3, Wt,
                                                pool, G_ * 64 + G_);
    k_colscan<<<(NB_ + 3) / 4, 256, 0, stream>>>(cnt_all, bcnt, bin_blocks, NB_);
    k_bscan<<<1, 256, 0, stream>>>(bcnt, bbase, NB_, E_);
    k_bucket<<<bin_blocks, 256, 0, stream>>>(srcp, dstp, bbase, cnt_all,
                                             staging, E_, NB_);
    k_sort<<<NB_, 256, 0, stream>>>(staging, bbase, csr_s, rowptr, rowend,
                                    dinv, N_, E_);

    const int gemm_blocks = (N_ + 63) / 64;
    const int agg_blocks  = (N_ + 3) / 4;
    const int wf_blocks   = (E_ + 255) / 256;

    // Fused wfill + Layer-1 GEMM
    k_wfgemm1<<<wf_blocks + gemm_blocks, 256, 0, stream>>>(
        csr_s, dinv, csr_w, E_, N_, wf_blocks, x, Wt, hW);
    k_agg<1><<<agg_blocks, 256, 0, stream>>>(hW, rowptr, rowend, csr_s, csr_w,
                                             dinv, aggb, N_, E_);
    // Layer 2
    k_gemm<true, unsigned short><<<gemm_blocks, 256, 0, stream>>>(aggb, Wt + 4096,
                                                                  b1, hW, N_);
    k_agg<2><<<agg_blocks, 256, 0, stream>>>(hW, rowptr, rowend, csr_s, csr_w,
                                             dinv, aggb, N_, E_);
    // Layer 3
    k_gemm<true, unsigned short><<<gemm_blocks, 256, 0, stream>>>(aggb, Wt + 8192,
                                                                  b2, hW, N_);
    k_agg<3><<<agg_blocks, 256, 0, stream>>>(hW, rowptr, rowend, csr_s, csr_w,
                                             dinv, aggb, N_, E_);

    // Pool (b3 folded into final) + classifier
    k_pool<<<(N_ + 63) / 64, 64, 0, stream>>>(aggb, bat, pool, cnt, N_);
    k_final<<<G_, 64, 0, stream>>>(pool, cnt, b3, Wl, bl, out);
}